// Round 1
// baseline (1546.911 us; speedup 1.0000x reference)
//
#include <hip/hip_runtime.h>
#include <cstdint>
#include <cstddef>

#define DD 2048
#define LL 2048
#define BB 4
#define MM (BB * LL) // 8192

typedef __bf16 bf16;
typedef __bf16 bf16x8 __attribute__((ext_vector_type(8)));
typedef float f32x4 __attribute__((ext_vector_type(4)));

// ---------------------------------------------------------------------------
// async global -> LDS, 16B per lane (wave-uniform base + lane*16 layout)
// ---------------------------------------------------------------------------
__device__ __forceinline__ void gload16(const void* g, void* l) {
    __builtin_amdgcn_global_load_lds(
        (const __attribute__((address_space(1))) void*)g,
        (__attribute__((address_space(3))) void*)l, 16, 0, 0);
}

// ---------------------------------------------------------------------------
// fp32 -> bf16 conversion (8 elements/thread)
// ---------------------------------------------------------------------------
__global__ __launch_bounds__(256) void cvt_f32_bf16(const float* __restrict__ s,
                                                    bf16* __restrict__ d, int n8) {
    int i = blockIdx.x * 256 + threadIdx.x;
    if (i >= n8) return;
    const float4* sp = (const float4*)s + (size_t)i * 2;
    float4 a = sp[0], b = sp[1];
    bf16x8 o;
    o[0] = (bf16)a.x; o[1] = (bf16)a.y; o[2] = (bf16)a.z; o[3] = (bf16)a.w;
    o[4] = (bf16)b.x; o[5] = (bf16)b.y; o[6] = (bf16)b.z; o[7] = (bf16)b.w;
    *((bf16x8*)d + i) = o;
}

// ---------------------------------------------------------------------------
// GEMM: C[m,n] = sum_k A[m,k] * B[n,k] (+ bias[n]).  A: MxK bf16 row-major,
// B: NxK bf16 row-major.  128x128 block tile, BK=32, 256 threads (4 waves),
// wave -> 64x64 via 4x4 grid of 16x16x32 bf16 MFMA.  m97-style staging via
// global_load_lds dwordx4.
// ---------------------------------------------------------------------------
template <int OUTF32>
__global__ __launch_bounds__(256) void gemm_bt(const bf16* __restrict__ A,
                                               const bf16* __restrict__ Bm,
                                               const float* __restrict__ bias,
                                               void* __restrict__ C,
                                               int Mdim, int Ndim, int Kdim) {
    __shared__ bf16 As[128 * 32];
    __shared__ bf16 Bs[128 * 32];
    const int tid = threadIdx.x;
    const int m0 = blockIdx.x * 128, n0 = blockIdx.y * 128;
    // staging: thread i -> row i>>2 (and +64), cols (i&3)*8 ; LDS offset tid*8
    const int sr = tid >> 2, sc = (tid & 3) << 3;
    const bf16* gA0 = A + (size_t)(m0 + sr) * Kdim + sc;
    const bf16* gA1 = A + (size_t)(m0 + 64 + sr) * Kdim + sc;
    const bf16* gB0 = Bm + (size_t)(n0 + sr) * Kdim + sc;
    const bf16* gB1 = Bm + (size_t)(n0 + 64 + sr) * Kdim + sc;
    bf16* lA0 = As + tid * 8;
    bf16* lA1 = As + 2048 + tid * 8;
    bf16* lB0 = Bs + tid * 8;
    bf16* lB1 = Bs + 2048 + tid * 8;

    const int wave = tid >> 6, lane = tid & 63;
    const int wm = (wave >> 1) << 6, wn = (wave & 1) << 6;
    const int fm = lane & 15, fg = lane >> 4; // frag row, k-group

    f32x4 acc[4][4];
#pragma unroll
    for (int i = 0; i < 4; i++)
#pragma unroll
        for (int j = 0; j < 4; j++) acc[i][j] = (f32x4){0.f, 0.f, 0.f, 0.f};

    for (int k0 = 0; k0 < Kdim; k0 += 32) {
        gload16(gA0, lA0);
        gload16(gA1, lA1);
        gload16(gB0, lB0);
        gload16(gB1, lB1);
        gA0 += 32; gA1 += 32; gB0 += 32; gB1 += 32;
        __syncthreads(); // drains vmcnt -> LDS tiles ready

        bf16x8 af[4], bfr[4];
#pragma unroll
        for (int i = 0; i < 4; i++)
            af[i] = *(const bf16x8*)(As + (wm + i * 16 + fm) * 32 + fg * 8);
#pragma unroll
        for (int j = 0; j < 4; j++)
            bfr[j] = *(const bf16x8*)(Bs + (wn + j * 16 + fm) * 32 + fg * 8);
#pragma unroll
        for (int i = 0; i < 4; i++)
#pragma unroll
            for (int j = 0; j < 4; j++)
                acc[i][j] = __builtin_amdgcn_mfma_f32_16x16x32_bf16(
                    af[i], bfr[j], acc[i][j], 0, 0, 0);
        __syncthreads(); // all waves done reading before next staging overwrite
    }

    // epilogue: D[row][col], col = lane&15, row = (lane>>4)*4 + r  [m89/m91]
#pragma unroll
    for (int j = 0; j < 4; j++) {
        const int col = n0 + wn + j * 16 + fm;
        const float bv = bias[col];
#pragma unroll
        for (int i = 0; i < 4; i++) {
#pragma unroll
            for (int r = 0; r < 4; r++) {
                const int row = m0 + wm + i * 16 + fg * 4 + r;
                float val = acc[i][j][r] + bv;
                if (OUTF32)
                    ((float*)C)[(size_t)row * Ndim + col] = val;
                else
                    ((bf16*)C)[(size_t)row * Ndim + col] = (bf16)val;
            }
        }
    }
}

// ---------------------------------------------------------------------------
// Depthwise causal conv (width 3) on q and k, kv = conv(k)*v, and transpose
// (B,L,E) -> (B,E,L).  Tile 32(l) x 32(e), LDS padded +1.
// y[l] = w0*x[l-2] + w1*x[l-1] + w2*x[l] + b
// ---------------------------------------------------------------------------
__global__ __launch_bounds__(256) void dwconv_kv(
    const bf16* __restrict__ q, const bf16* __restrict__ k, const bf16* __restrict__ v,
    const float* __restrict__ cqw, const float* __restrict__ cqb,
    const float* __restrict__ ckw, const float* __restrict__ ckb,
    bf16* __restrict__ qcT, bf16* __restrict__ kvT) {
    __shared__ float qs[34][33];
    __shared__ float ks[34][33];
    __shared__ float vs[32][33];
    const int b = blockIdx.z;
    const int l0 = blockIdx.x * 32, e0 = blockIdx.y * 32;
    const int tid = threadIdx.x;
    const int el = tid & 31, lr = tid >> 5;
#pragma unroll
    for (int p = 0; p < 5; ++p) {
        int r = lr + p * 8;
        if (r < 34) {
            int lg = l0 - 2 + r;
            float qv = 0.f, kv_ = 0.f;
            if (lg >= 0) {
                size_t idx = ((size_t)b * LL + lg) * DD + e0 + el;
                qv = (float)q[idx];
                kv_ = (float)k[idx];
            }
            qs[r][el] = qv;
            ks[r][el] = kv_;
        }
    }
#pragma unroll
    for (int p = 0; p < 4; ++p) {
        int r = lr + p * 8;
        size_t idx = ((size_t)b * LL + l0 + r) * DD + e0 + el;
        vs[r][el] = (float)v[idx];
    }
    __syncthreads();
    const int li = tid & 31;
#pragma unroll
    for (int p = 0; p < 4; ++p) {
        int ei = (tid >> 5) + p * 8;
        int d = e0 + ei;
        float q0 = cqw[d * 3], q1 = cqw[d * 3 + 1], q2 = cqw[d * 3 + 2];
        float k0 = ckw[d * 3], k1 = ckw[d * 3 + 1], k2 = ckw[d * 3 + 2];
        float qc = q0 * qs[li][ei] + q1 * qs[li + 1][ei] + q2 * qs[li + 2][ei] + cqb[d];
        float kc = k0 * ks[li][ei] + k1 * ks[li + 1][ei] + k2 * ks[li + 2][ei] + ckb[d];
        float kvv = kc * vs[li][ei];
        size_t o = ((size_t)b * DD + d) * LL + l0 + li;
        qcT[o] = (bf16)qc;
        kvT[o] = (bf16)kvv;
    }
}

// ---------------------------------------------------------------------------
// Causal long conv + D-skip + q gating, per (b,d) sequence.
// y[l] = sum_{m<=l} kv[m]*kern[l-m];  out = (y + kv*Dskip)*qc  (bf16 out, (B,E,L))
// Lane t owns outputs l = 8t..8t+7; m processed in aligned blocks of 8 with a
// sliding pair of aligned 8-float kern windows (KA=kern[8s-8..], KB=kern[8s..]).
// ---------------------------------------------------------------------------
__global__ __launch_bounds__(256) void longconv_gate(
    const bf16* __restrict__ kvT, const bf16* __restrict__ qcT,
    const float* __restrict__ kern, const float* __restrict__ Dskip,
    bf16* __restrict__ ygT) {
    __shared__ float skv[2048];
    __shared__ float skn[2048];
    const int d = blockIdx.x & (DD - 1);
    const int b = blockIdx.x >> 11;
    const int tid = threadIdx.x;
    {
        bf16x8 kv8v = *(const bf16x8*)(kvT + ((size_t)b * DD + d) * LL + tid * 8);
#pragma unroll
        for (int j = 0; j < 8; j++) skv[tid * 8 + j] = (float)kv8v[j];
        const float4* kp = (const float4*)(kern + (size_t)d * LL) + tid * 2;
        float4 ka = kp[0], kb = kp[1];
        float4* sp = (float4*)skn + tid * 2;
        sp[0] = ka;
        sp[1] = kb;
    }
    __syncthreads();

    const int t = tid;
    float y[8] = {0.f, 0.f, 0.f, 0.f, 0.f, 0.f, 0.f, 0.f};
    float KA[8], KB[8], kv8[8];
    if (t >= 1) {
#pragma unroll
        for (int c = 0; c < 8; c++) {
            KB[c] = skn[8 * t + c];
            KA[c] = skn[8 * t - 8 + c];
        }
    }
    const int tmax = ((tid >> 6) << 6) + 63; // wave-uniform loop bound
    for (int j = 0; j < tmax; ++j) {
        if (j < t) {
            const int mb = 8 * j;
#pragma unroll
            for (int e = 0; e < 8; e++) kv8[e] = skv[mb + e];
#pragma unroll
            for (int c = 0; c < 8; c++)
#pragma unroll
                for (int e = 0; e < 8; e++)
                    y[c] += kv8[e] * (c >= e ? KB[c - e] : KA[8 + c - e]);
            const int s1 = t - j - 1; // next window index
#pragma unroll
            for (int c = 0; c < 8; c++) KB[c] = KA[c];
            if (s1 >= 1) {
#pragma unroll
                for (int c = 0; c < 8; c++) KA[c] = skn[8 * s1 - 8 + c];
            }
        }
    }
    // diagonal (triangular) block j == t
    {
        float k07[8];
#pragma unroll
        for (int c = 0; c < 8; c++) k07[c] = skn[c];
#pragma unroll
        for (int e = 0; e < 8; e++) kv8[e] = skv[8 * t + e];
#pragma unroll
        for (int c = 0; c < 8; c++)
#pragma unroll
            for (int e = 0; e <= c; e++) y[c] += kv8[e] * k07[c - e];
    }
    // gating epilogue
    const float dsk = Dskip[d];
    bf16x8 qc8 = *(const bf16x8*)(qcT + ((size_t)b * DD + d) * LL + tid * 8);
    bf16x8 o;
#pragma unroll
    for (int c = 0; c < 8; c++) {
        float kvl = skv[8 * t + c];
        float val = (y[c] + kvl * dsk) * (float)qc8[c];
        o[c] = (bf16)val;
    }
    *(bf16x8*)(ygT + ((size_t)b * DD + d) * LL + tid * 8) = o;
}

// ---------------------------------------------------------------------------
// bf16 transpose (B, D, L) -> (B, L, D), 32x32 tiles
// ---------------------------------------------------------------------------
__global__ __launch_bounds__(256) void transpose_dl(const bf16* __restrict__ src,
                                                    bf16* __restrict__ dst) {
    __shared__ bf16 ts[32][33];
    const int b = blockIdx.z;
    const int l0 = blockIdx.x * 32, d0 = blockIdx.y * 32;
    const int tid = threadIdx.x;
    const int c = tid & 31, r0 = tid >> 5;
#pragma unroll
    for (int p = 0; p < 4; p++) {
        int r = r0 + p * 8;
        ts[r][c] = src[((size_t)b * DD + d0 + r) * LL + l0 + c];
    }
    __syncthreads();
#pragma unroll
    for (int p = 0; p < 4; p++) {
        int r = r0 + p * 8; // local l index
        dst[((size_t)b * LL + l0 + r) * DD + d0 + c] = ts[c][r];
    }
}

// ---------------------------------------------------------------------------
// launch
// ---------------------------------------------------------------------------
extern "C" void kernel_launch(void* const* d_in, const int* in_sizes, int n_in,
                              void* d_out, int out_size, void* d_ws, size_t ws_size,
                              hipStream_t stream) {
    const float* u   = (const float*)d_in[0];
    const float* Wq  = (const float*)d_in[1];
    const float* bq  = (const float*)d_in[2];
    const float* Wk  = (const float*)d_in[3];
    const float* bk  = (const float*)d_in[4];
    const float* Wv  = (const float*)d_in[5];
    const float* bv  = (const float*)d_in[6];
    const float* cqw = (const float*)d_in[7];
    const float* cqb = (const float*)d_in[8];
    const float* ckw = (const float*)d_in[9];
    const float* ckb = (const float*)d_in[10];
    const float* ssm = (const float*)d_in[11];
    const float* Dsk = (const float*)d_in[12];
    const float* Wo  = (const float*)d_in[13];
    const float* bo  = (const float*)d_in[14];

    char* w = (char*)d_ws;
    bf16* u_bf  = (bf16*)(w);                  // 33.5 MB (reused later as ygT)
    bf16* Wq_bf = (bf16*)(w + 33554432ull);    // 8.4 MB
    bf16* Wk_bf = (bf16*)(w + 41943040ull);
    bf16* Wv_bf = (bf16*)(w + 50331648ull);
    bf16* Wo_bf = (bf16*)(w + 58720256ull);
    bf16* q_bf  = (bf16*)(w + 67108864ull);    // 33.5 MB (reused later as ygTT)
    bf16* k_bf  = (bf16*)(w + 100663296ull);
    bf16* v_bf  = (bf16*)(w + 134217728ull);
    bf16* qcT   = (bf16*)(w + 167772160ull);
    bf16* kvT   = (bf16*)(w + 201326592ull);
    // total ws use: 234,881,024 bytes

    // fp32 -> bf16 conversions
    cvt_f32_bf16<<<8192, 256, 0, stream>>>(u, u_bf, MM * DD / 8);
    cvt_f32_bf16<<<2048, 256, 0, stream>>>(Wq, Wq_bf, DD * DD / 8);
    cvt_f32_bf16<<<2048, 256, 0, stream>>>(Wk, Wk_bf, DD * DD / 8);
    cvt_f32_bf16<<<2048, 256, 0, stream>>>(Wv, Wv_bf, DD * DD / 8);
    cvt_f32_bf16<<<2048, 256, 0, stream>>>(Wo, Wo_bf, DD * DD / 8);

    // q/k/v projections
    dim3 gg(MM / 128, DD / 128);
    gemm_bt<0><<<gg, 256, 0, stream>>>(u_bf, Wq_bf, bq, q_bf, MM, DD, DD);
    gemm_bt<0><<<gg, 256, 0, stream>>>(u_bf, Wk_bf, bk, k_bf, MM, DD, DD);
    gemm_bt<0><<<gg, 256, 0, stream>>>(u_bf, Wv_bf, bv, v_bf, MM, DD, DD);

    // depthwise convs + kv + transpose to (B,E,L)
    dim3 gc(LL / 32, DD / 32, BB);
    dwconv_kv<<<gc, 256, 0, stream>>>(q_bf, k_bf, v_bf, cqw, cqb, ckw, ckb, qcT, kvT);

    // causal long conv + gating
    bf16* ygT = u_bf; // reuse
    longconv_gate<<<BB * DD, 256, 0, stream>>>(kvT, qcT, ssm, Dsk, ygT);

    // transpose back to (B,L,E)
    bf16* ygTT = q_bf; // reuse
    transpose_dl<<<gc, 256, 0, stream>>>(ygT, ygTT);

    // output projection -> fp32 d_out
    gemm_bt<1><<<gg, 256, 0, stream>>>(ygTT, Wo_bf, bo, d_out, MM, DD, DD);
}

// Round 2
// 767.400 us; speedup vs baseline: 2.0158x; 2.0158x over previous
//
#include <hip/hip_runtime.h>
#include <cstdint>
#include <cstddef>

#define DD 2048
#define LL 2048
#define BB 4
#define MM (BB * LL) // 8192

typedef __bf16 bf16;
typedef __bf16 bf16x8 __attribute__((ext_vector_type(8)));
typedef __bf16 bf16x4 __attribute__((ext_vector_type(4)));
typedef float f32x4 __attribute__((ext_vector_type(4)));

// ---------------------------------------------------------------------------
// async global -> LDS, 16B per lane (wave-uniform base + lane*16 layout)
// ---------------------------------------------------------------------------
__device__ __forceinline__ void gload16(const void* g, void* l) {
    __builtin_amdgcn_global_load_lds(
        (const __attribute__((address_space(1))) void*)g,
        (__attribute__((address_space(3))) void*)l, 16, 0, 0);
}

// ---------------------------------------------------------------------------
// fp32 -> bf16 conversion (8 elements/thread)
// ---------------------------------------------------------------------------
__global__ __launch_bounds__(256) void cvt_f32_bf16(const float* __restrict__ s,
                                                    bf16* __restrict__ d, int n8) {
    int i = blockIdx.x * 256 + threadIdx.x;
    if (i >= n8) return;
    const float4* sp = (const float4*)s + (size_t)i * 2;
    float4 a = sp[0], b = sp[1];
    bf16x8 o;
    o[0] = (bf16)a.x; o[1] = (bf16)a.y; o[2] = (bf16)a.z; o[3] = (bf16)a.w;
    o[4] = (bf16)b.x; o[5] = (bf16)b.y; o[6] = (bf16)b.z; o[7] = (bf16)b.w;
    *((bf16x8*)d + i) = o;
}

// ---------------------------------------------------------------------------
// GEMM: C[m,n] = sum_k A[m,k] * B[n,k] (+ bias[n]).  (unchanged, verified)
// ---------------------------------------------------------------------------
template <int OUTF32>
__global__ __launch_bounds__(256) void gemm_bt(const bf16* __restrict__ A,
                                               const bf16* __restrict__ Bm,
                                               const float* __restrict__ bias,
                                               void* __restrict__ C,
                                               int Mdim, int Ndim, int Kdim) {
    __shared__ bf16 As[128 * 32];
    __shared__ bf16 Bs[128 * 32];
    const int tid = threadIdx.x;
    const int m0 = blockIdx.x * 128, n0 = blockIdx.y * 128;
    const int sr = tid >> 2, sc = (tid & 3) << 3;
    const bf16* gA0 = A + (size_t)(m0 + sr) * Kdim + sc;
    const bf16* gA1 = A + (size_t)(m0 + 64 + sr) * Kdim + sc;
    const bf16* gB0 = Bm + (size_t)(n0 + sr) * Kdim + sc;
    const bf16* gB1 = Bm + (size_t)(n0 + 64 + sr) * Kdim + sc;
    bf16* lA0 = As + tid * 8;
    bf16* lA1 = As + 2048 + tid * 8;
    bf16* lB0 = Bs + tid * 8;
    bf16* lB1 = Bs + 2048 + tid * 8;

    const int wave = tid >> 6, lane = tid & 63;
    const int wm = (wave >> 1) << 6, wn = (wave & 1) << 6;
    const int fm = lane & 15, fg = lane >> 4;

    f32x4 acc[4][4];
#pragma unroll
    for (int i = 0; i < 4; i++)
#pragma unroll
        for (int j = 0; j < 4; j++) acc[i][j] = (f32x4){0.f, 0.f, 0.f, 0.f};

    for (int k0 = 0; k0 < Kdim; k0 += 32) {
        gload16(gA0, lA0);
        gload16(gA1, lA1);
        gload16(gB0, lB0);
        gload16(gB1, lB1);
        gA0 += 32; gA1 += 32; gB0 += 32; gB1 += 32;
        __syncthreads();

        bf16x8 af[4], bfr[4];
#pragma unroll
        for (int i = 0; i < 4; i++)
            af[i] = *(const bf16x8*)(As + (wm + i * 16 + fm) * 32 + fg * 8);
#pragma unroll
        for (int j = 0; j < 4; j++)
            bfr[j] = *(const bf16x8*)(Bs + (wn + j * 16 + fm) * 32 + fg * 8);
#pragma unroll
        for (int i = 0; i < 4; i++)
#pragma unroll
            for (int j = 0; j < 4; j++)
                acc[i][j] = __builtin_amdgcn_mfma_f32_16x16x32_bf16(
                    af[i], bfr[j], acc[i][j], 0, 0, 0);
        __syncthreads();
    }

#pragma unroll
    for (int j = 0; j < 4; j++) {
        const int col = n0 + wn + j * 16 + fm;
        const float bv = bias[col];
#pragma unroll
        for (int i = 0; i < 4; i++) {
#pragma unroll
            for (int r = 0; r < 4; r++) {
                const int row = m0 + wm + i * 16 + fg * 4 + r;
                float val = acc[i][j][r] + bv;
                if (OUTF32)
                    ((float*)C)[(size_t)row * Ndim + col] = val;
                else
                    ((bf16*)C)[(size_t)row * Ndim + col] = (bf16)val;
            }
        }
    }
}

// ---------------------------------------------------------------------------
// Depthwise causal conv (width 3) on q and k, kv = conv(k)*v, transpose
// (B,L,E) -> (B,E,L).  (unchanged, verified)
// ---------------------------------------------------------------------------
__global__ __launch_bounds__(256) void dwconv_kv(
    const bf16* __restrict__ q, const bf16* __restrict__ k, const bf16* __restrict__ v,
    const float* __restrict__ cqw, const float* __restrict__ cqb,
    const float* __restrict__ ckw, const float* __restrict__ ckb,
    bf16* __restrict__ qcT, bf16* __restrict__ kvT) {
    __shared__ float qs[34][33];
    __shared__ float ks[34][33];
    __shared__ float vs[32][33];
    const int b = blockIdx.z;
    const int l0 = blockIdx.x * 32, e0 = blockIdx.y * 32;
    const int tid = threadIdx.x;
    const int el = tid & 31, lr = tid >> 5;
#pragma unroll
    for (int p = 0; p < 5; ++p) {
        int r = lr + p * 8;
        if (r < 34) {
            int lg = l0 - 2 + r;
            float qv = 0.f, kv_ = 0.f;
            if (lg >= 0) {
                size_t idx = ((size_t)b * LL + lg) * DD + e0 + el;
                qv = (float)q[idx];
                kv_ = (float)k[idx];
            }
            qs[r][el] = qv;
            ks[r][el] = kv_;
        }
    }
#pragma unroll
    for (int p = 0; p < 4; ++p) {
        int r = lr + p * 8;
        size_t idx = ((size_t)b * LL + l0 + r) * DD + e0 + el;
        vs[r][el] = (float)v[idx];
    }
    __syncthreads();
    const int li = tid & 31;
#pragma unroll
    for (int p = 0; p < 4; ++p) {
        int ei = (tid >> 5) + p * 8;
        int d = e0 + ei;
        float q0 = cqw[d * 3], q1 = cqw[d * 3 + 1], q2 = cqw[d * 3 + 2];
        float k0 = ckw[d * 3], k1 = ckw[d * 3 + 1], k2 = ckw[d * 3 + 2];
        float qc = q0 * qs[li][ei] + q1 * qs[li + 1][ei] + q2 * qs[li + 2][ei] + cqb[d];
        float kc = k0 * ks[li][ei] + k1 * ks[li + 1][ei] + k2 * ks[li + 2][ei] + ckb[d];
        float kvv = kc * vs[li][ei];
        size_t o = ((size_t)b * DD + d) * LL + l0 + li;
        qcT[o] = (bf16)qc;
        kvT[o] = (bf16)kvv;
    }
}

// ---------------------------------------------------------------------------
// Causal long conv + D-skip + q gating via Toeplitz MFMA.
// One block (128 thr = 2 waves) per d; all 4 batches ride in the MFMA N-dim.
//
// y[b,l] = sum_j kern[l-j] kv[b,j].  16x16x32 MFMA: D[m][n] = sum_k A[m][k]B[n][k]
//   A[m][k] = kern[delta + m - k]          (Toeplitz, shared across columns)
//   B[(b,pp)][k] = kv[b, kBase + k + 16pp - 48]
// => D[m][(b,pp)] = y[b, l0 + m + 16pp - 48],  delta = l0 - kBase.
// Stripe i (64 l's [64i,64i+64)): l0 = 64i + 48; kBase in [0, 64i+32] step 32
// <=> delta = 16 + 32*it, stripe i active iff it <= 4s + 2w + 1 (i = 2s+w).
// A-frag built once per delta from reversed fp32 kernel in LDS, reused by all
// 16 stripes of the wave.  kv zero-padded 48 front in LDS (causal head).
// ---------------------------------------------------------------------------
__global__ __launch_bounds__(128, 2) void longconv_gate(
    const bf16* __restrict__ kvT, const bf16* __restrict__ qcT,
    const float* __restrict__ kern, const float* __restrict__ Dskip,
    bf16* __restrict__ ygT) {
    __shared__ bf16 kv_ls[4 * 2112];
    __shared__ float krev_f[2112];
    const int d = blockIdx.x;
    const int tid = threadIdx.x;

    // ---- stage kv (4 batches) with 48-elem zero head, 2112 stride ----
    {
        const int bb = tid >> 5, t32 = tid & 31;
#pragma unroll
        for (int c = 0; c < 8; ++c) {
            const int l = (c * 32 + t32) * 8;
            bf16x8 v = *(const bf16x8*)(kvT + ((size_t)bb * DD + d) * LL + l);
            *(bf16x8*)&kv_ls[2112 * bb + 48 + l] = v;
        }
        if (tid < 48) {
#pragma unroll
            for (int b2 = 0; b2 < 4; b2++) kv_ls[2112 * b2 + tid] = (bf16)0.f;
        } else if (tid < 64) {
#pragma unroll
            for (int b2 = 0; b2 < 4; b2++) kv_ls[2112 * b2 + 2048 + tid] = (bf16)0.f;
        }
    }
    // ---- stage reversed kernel (fp32): krev_f[x] = kern[d, 2047-x], pad 0 ----
    {
        const float* kr = kern + (size_t)d * LL;
#pragma unroll
        for (int c = 0; c < 16; ++c) {
            const int x = c * 128 + tid;
            krev_f[x] = kr[2047 - x];
        }
        if (tid < 64) krev_f[2048 + tid] = 0.f;
    }
    __syncthreads();

    const int lane = tid & 63;
    const int w = __builtin_amdgcn_readfirstlane(tid >> 6); // wave id (scalar)
    const int n = lane & 15, q = lane >> 4; // n = MFMA col (and A row m), q = quad
    const int b = n & 3, pp = n >> 2;
    const int cB = 2112 * b + 16 * pp + 8 * q;

    f32x4 acc[16];
#pragma unroll
    for (int s = 0; s < 16; s++) acc[s] = (f32x4){0.f, 0.f, 0.f, 0.f};

    for (int it = 0; it < 64; ++it) {
        // A-frag: A[m][k] = kern[delta + m - k] = krev_f[2031 - 32it - m + 8q + j]
        const int as = 2031 - 32 * it - n + 8 * q;
        float af[8];
#pragma unroll
        for (int j = 0; j < 8; j++) af[j] = krev_f[as + j];
        bf16x8 a;
#pragma unroll
        for (int j = 0; j < 8; j++) a[j] = (bf16)af[j];

        const int bbase = cB + 64 * w + 32 - 32 * it;
#pragma unroll
        for (int h = 0; h < 2; ++h) {
            bf16x8 bfr[8];
#pragma unroll
            for (int s8 = 0; s8 < 8; s8++) {
                const int s = h * 8 + s8;
                if (it <= 4 * s + 2 * w + 1)
                    bfr[s8] = *(const bf16x8*)&kv_ls[bbase + 128 * s];
            }
#pragma unroll
            for (int s8 = 0; s8 < 8; s8++) {
                const int s = h * 8 + s8;
                if (it <= 4 * s + 2 * w + 1)
                    acc[s] = __builtin_amdgcn_mfma_f32_16x16x32_bf16(
                        a, bfr[s8], acc[s], 0, 0, 0);
            }
        }
    }

    // ---- epilogue: out = (y + kv*Dskip)*qc ; D row = 4q + r, col = n ----
    const float dsk = Dskip[d];
#pragma unroll
    for (int s = 0; s < 16; s++) {
        const int i = 2 * s + w;
        const int l = 64 * i + 16 * pp + 4 * q;
        const size_t gb = ((size_t)b * DD + d) * LL + l;
        bf16x4 qc4 = *(const bf16x4*)&qcT[gb];
        bf16x4 kv4 = *(const bf16x4*)&kv_ls[2112 * b + 48 + l];
        bf16x4 o;
#pragma unroll
        for (int r = 0; r < 4; r++) {
            float val = (acc[s][r] + (float)kv4[r] * dsk) * (float)qc4[r];
            o[r] = (bf16)val;
        }
        *(bf16x4*)&ygT[gb] = o;
    }
}

// ---------------------------------------------------------------------------
// bf16 transpose (B, D, L) -> (B, L, D), 32x32 tiles (unchanged)
// ---------------------------------------------------------------------------
__global__ __launch_bounds__(256) void transpose_dl(const bf16* __restrict__ src,
                                                    bf16* __restrict__ dst) {
    __shared__ bf16 ts[32][33];
    const int b = blockIdx.z;
    const int l0 = blockIdx.x * 32, d0 = blockIdx.y * 32;
    const int tid = threadIdx.x;
    const int c = tid & 31, r0 = tid >> 5;
#pragma unroll
    for (int p = 0; p < 4; p++) {
        int r = r0 + p * 8;
        ts[r][c] = src[((size_t)b * DD + d0 + r) * LL + l0 + c];
    }
    __syncthreads();
#pragma unroll
    for (int p = 0; p < 4; p++) {
        int r = r0 + p * 8; // local l index
        dst[((size_t)b * LL + l0 + r) * DD + d0 + c] = ts[c][r];
    }
}

// ---------------------------------------------------------------------------
// launch
// ---------------------------------------------------------------------------
extern "C" void kernel_launch(void* const* d_in, const int* in_sizes, int n_in,
                              void* d_out, int out_size, void* d_ws, size_t ws_size,
                              hipStream_t stream) {
    const float* u   = (const float*)d_in[0];
    const float* Wq  = (const float*)d_in[1];
    const float* bq  = (const float*)d_in[2];
    const float* Wk  = (const float*)d_in[3];
    const float* bk  = (const float*)d_in[4];
    const float* Wv  = (const float*)d_in[5];
    const float* bv  = (const float*)d_in[6];
    const float* cqw = (const float*)d_in[7];
    const float* cqb = (const float*)d_in[8];
    const float* ckw = (const float*)d_in[9];
    const float* ckb = (const float*)d_in[10];
    const float* ssm = (const float*)d_in[11];
    const float* Dsk = (const float*)d_in[12];
    const float* Wo  = (const float*)d_in[13];
    const float* bo  = (const float*)d_in[14];

    char* w = (char*)d_ws;
    bf16* u_bf  = (bf16*)(w);                  // 33.5 MB (reused later as ygT)
    bf16* Wq_bf = (bf16*)(w + 33554432ull);    // 8.4 MB
    bf16* Wk_bf = (bf16*)(w + 41943040ull);
    bf16* Wv_bf = (bf16*)(w + 50331648ull);
    bf16* Wo_bf = (bf16*)(w + 58720256ull);
    bf16* q_bf  = (bf16*)(w + 67108864ull);    // 33.5 MB (reused later as ygTT)
    bf16* k_bf  = (bf16*)(w + 100663296ull);
    bf16* v_bf  = (bf16*)(w + 134217728ull);
    bf16* qcT   = (bf16*)(w + 167772160ull);
    bf16* kvT   = (bf16*)(w + 201326592ull);

    // fp32 -> bf16 conversions
    cvt_f32_bf16<<<8192, 256, 0, stream>>>(u, u_bf, MM * DD / 8);
    cvt_f32_bf16<<<2048, 256, 0, stream>>>(Wq, Wq_bf, DD * DD / 8);
    cvt_f32_bf16<<<2048, 256, 0, stream>>>(Wk, Wk_bf, DD * DD / 8);
    cvt_f32_bf16<<<2048, 256, 0, stream>>>(Wv, Wv_bf, DD * DD / 8);
    cvt_f32_bf16<<<2048, 256, 0, stream>>>(Wo, Wo_bf, DD * DD / 8);

    // q/k/v projections
    dim3 gg(MM / 128, DD / 128);
    gemm_bt<0><<<gg, 256, 0, stream>>>(u_bf, Wq_bf, bq, q_bf, MM, DD, DD);
    gemm_bt<0><<<gg, 256, 0, stream>>>(u_bf, Wk_bf, bk, k_bf, MM, DD, DD);
    gemm_bt<0><<<gg, 256, 0, stream>>>(u_bf, Wv_bf, bv, v_bf, MM, DD, DD);

    // depthwise convs + kv + transpose to (B,E,L)
    dim3 gc(LL / 32, DD / 32, BB);
    dwconv_kv<<<gc, 256, 0, stream>>>(q_bf, k_bf, v_bf, cqw, cqb, ckw, ckb, qcT, kvT);

    // causal long conv (Toeplitz MFMA) + gating
    bf16* ygT = u_bf; // reuse
    longconv_gate<<<DD, 128, 0, stream>>>(kvT, qcT, ssm, Dsk, ygT);

    // transpose back to (B,L,E)
    bf16* ygTT = q_bf; // reuse
    transpose_dl<<<gc, 256, 0, stream>>>(ygT, ygTT);

    // output projection -> fp32 d_out
    gemm_bt<1><<<gg, 256, 0, stream>>>(ygTT, Wo_bf, bo, d_out, MM, DD, DD);
}

// Round 3
// 664.246 us; speedup vs baseline: 2.3288x; 1.1553x over previous
//
#include <hip/hip_runtime.h>
#include <cstdint>
#include <cstddef>

#define DD 2048
#define LL 2048
#define BB 4
#define MM (BB * LL) // 8192
#define NN 6144      // fused q|k|v output columns

typedef __bf16 bf16;
typedef __bf16 bf16x8 __attribute__((ext_vector_type(8)));
typedef __bf16 bf16x4 __attribute__((ext_vector_type(4)));
typedef __bf16 bf16x2 __attribute__((ext_vector_type(2)));
typedef float f32x4 __attribute__((ext_vector_type(4)));

// ---------------------------------------------------------------------------
// async global -> LDS, 16B per lane (wave-uniform base + lane*16 layout)
// ---------------------------------------------------------------------------
__device__ __forceinline__ void gload16(const void* g, void* l) {
    __builtin_amdgcn_global_load_lds(
        (const __attribute__((address_space(1))) void*)g,
        (__attribute__((address_space(3))) void*)l, 16, 0, 0);
}

// ---------------------------------------------------------------------------
// fp32 -> bf16 conversion (8 elements/thread)
// ---------------------------------------------------------------------------
__global__ __launch_bounds__(256) void cvt_f32_bf16(const float* __restrict__ s,
                                                    bf16* __restrict__ d, int n8) {
    int i = blockIdx.x * 256 + threadIdx.x;
    if (i >= n8) return;
    const float4* sp = (const float4*)s + (size_t)i * 2;
    float4 a = sp[0], b = sp[1];
    bf16x8 o;
    o[0] = (bf16)a.x; o[1] = (bf16)a.y; o[2] = (bf16)a.z; o[3] = (bf16)a.w;
    o[4] = (bf16)b.x; o[5] = (bf16)b.y; o[6] = (bf16)b.z; o[7] = (bf16)b.w;
    *((bf16x8*)d + i) = o;
}

// ---------------------------------------------------------------------------
// Fused QKV GEMM: C[m,n] = sum_k A[m,k]*Wqkv[n,k] + bias(n), written
// TRANSPOSED: out[n][m] (bf16, (6144, 8192)).  128x128 tile, BK=32, m97-style
// K-loop; epilogue stages the C-tile to LDS as Ct[col][row] (pad +8 -> 2-way
// bank aliasing, free) then stores coalesced 256B runs of C^T.
// ---------------------------------------------------------------------------
__global__ __launch_bounds__(256) void gemm_qkv(const bf16* __restrict__ A,
                                                const bf16* __restrict__ Bm,
                                                const float* __restrict__ bq,
                                                const float* __restrict__ bk,
                                                const float* __restrict__ bv,
                                                bf16* __restrict__ CtOut) {
    __shared__ bf16 lds[128 * 136]; // union: staging (16 KB) / epilogue (34.8 KB)
    bf16* As = lds;
    bf16* Bs = lds + 4096;
    const int tid = threadIdx.x;
    const int m0 = blockIdx.x * 128, n0 = blockIdx.y * 128;
    const int sr = tid >> 2, sc = (tid & 3) << 3;
    const bf16* gA0 = A + (size_t)(m0 + sr) * DD + sc;
    const bf16* gA1 = A + (size_t)(m0 + 64 + sr) * DD + sc;
    const bf16* gB0 = Bm + (size_t)(n0 + sr) * DD + sc;
    const bf16* gB1 = Bm + (size_t)(n0 + 64 + sr) * DD + sc;
    bf16* lA0 = As + tid * 8;
    bf16* lA1 = As + 2048 + tid * 8;
    bf16* lB0 = Bs + tid * 8;
    bf16* lB1 = Bs + 2048 + tid * 8;

    const int wave = tid >> 6, lane = tid & 63;
    const int wm = (wave >> 1) << 6, wn = (wave & 1) << 6;
    const int fm = lane & 15, fg = lane >> 4;

    f32x4 acc[4][4];
#pragma unroll
    for (int i = 0; i < 4; i++)
#pragma unroll
        for (int j = 0; j < 4; j++) acc[i][j] = (f32x4){0.f, 0.f, 0.f, 0.f};

    for (int k0 = 0; k0 < DD; k0 += 32) {
        gload16(gA0, lA0);
        gload16(gA1, lA1);
        gload16(gB0, lB0);
        gload16(gB1, lB1);
        gA0 += 32; gA1 += 32; gB0 += 32; gB1 += 32;
        __syncthreads();

        bf16x8 af[4], bfr[4];
#pragma unroll
        for (int i = 0; i < 4; i++)
            af[i] = *(const bf16x8*)(As + (wm + i * 16 + fm) * 32 + fg * 8);
#pragma unroll
        for (int j = 0; j < 4; j++)
            bfr[j] = *(const bf16x8*)(Bs + (wn + j * 16 + fm) * 32 + fg * 8);
#pragma unroll
        for (int i = 0; i < 4; i++)
#pragma unroll
            for (int j = 0; j < 4; j++)
                acc[i][j] = __builtin_amdgcn_mfma_f32_16x16x32_bf16(
                    af[i], bfr[j], acc[i][j], 0, 0, 0);
        __syncthreads(); // also guarantees LDS safe to reuse after final iter
    }

    // ---- epilogue: bias (block lies fully in one of q/k/v since 2048%128==0)
    const float* bp = (n0 < 2048) ? bq : ((n0 < 4096) ? bk : bv);
    const int nb = n0 & 2047;
#pragma unroll
    for (int j = 0; j < 4; j++) {
        const int col = wn + j * 16 + fm;
        const float bvv = bp[nb + col];
#pragma unroll
        for (int i = 0; i < 4; i++) {
#pragma unroll
            for (int r = 0; r < 4; r++) {
                const int row = wm + i * 16 + fg * 4 + r;
                lds[col * 136 + row] = (bf16)(acc[i][j][r] + bvv);
            }
        }
    }
    __syncthreads();
    // ---- coalesced C^T store: 8 rounds x (16 cols x 256B contiguous) ----
    const int ccol = tid >> 4, chunk = tid & 15;
#pragma unroll
    for (int p = 0; p < 8; p++) {
        const int col = p * 16 + ccol;
        bf16x8 vv = *(const bf16x8*)&lds[col * 136 + chunk * 8];
        *(bf16x8*)(CtOut + (size_t)(n0 + col) * MM + m0 + chunk * 8) = vv;
    }
}

// ---------------------------------------------------------------------------
// GEMM (row-major out): C[m,n] = sum_k A[m,k]*B[n,k] + bias[n].  Used for the
// final projection (f32 out; 64B store segments are acceptable).
// ---------------------------------------------------------------------------
__global__ __launch_bounds__(256) void gemm_bt_f32(const bf16* __restrict__ A,
                                                   const bf16* __restrict__ Bm,
                                                   const float* __restrict__ bias,
                                                   float* __restrict__ C,
                                                   int Ndim, int Kdim) {
    __shared__ bf16 As[128 * 32];
    __shared__ bf16 Bs[128 * 32];
    const int tid = threadIdx.x;
    const int m0 = blockIdx.x * 128, n0 = blockIdx.y * 128;
    const int sr = tid >> 2, sc = (tid & 3) << 3;
    const bf16* gA0 = A + (size_t)(m0 + sr) * Kdim + sc;
    const bf16* gA1 = A + (size_t)(m0 + 64 + sr) * Kdim + sc;
    const bf16* gB0 = Bm + (size_t)(n0 + sr) * Kdim + sc;
    const bf16* gB1 = Bm + (size_t)(n0 + 64 + sr) * Kdim + sc;
    bf16* lA0 = As + tid * 8;
    bf16* lA1 = As + 2048 + tid * 8;
    bf16* lB0 = Bs + tid * 8;
    bf16* lB1 = Bs + 2048 + tid * 8;

    const int wave = tid >> 6, lane = tid & 63;
    const int wm = (wave >> 1) << 6, wn = (wave & 1) << 6;
    const int fm = lane & 15, fg = lane >> 4;

    f32x4 acc[4][4];
#pragma unroll
    for (int i = 0; i < 4; i++)
#pragma unroll
        for (int j = 0; j < 4; j++) acc[i][j] = (f32x4){0.f, 0.f, 0.f, 0.f};

    for (int k0 = 0; k0 < Kdim; k0 += 32) {
        gload16(gA0, lA0);
        gload16(gA1, lA1);
        gload16(gB0, lB0);
        gload16(gB1, lB1);
        gA0 += 32; gA1 += 32; gB0 += 32; gB1 += 32;
        __syncthreads();

        bf16x8 af[4], bfr[4];
#pragma unroll
        for (int i = 0; i < 4; i++)
            af[i] = *(const bf16x8*)(As + (wm + i * 16 + fm) * 32 + fg * 8);
#pragma unroll
        for (int j = 0; j < 4; j++)
            bfr[j] = *(const bf16x8*)(Bs + (wn + j * 16 + fm) * 32 + fg * 8);
#pragma unroll
        for (int i = 0; i < 4; i++)
#pragma unroll
            for (int j = 0; j < 4; j++)
                acc[i][j] = __builtin_amdgcn_mfma_f32_16x16x32_bf16(
                    af[i], bfr[j], acc[i][j], 0, 0, 0);
        __syncthreads();
    }

#pragma unroll
    for (int j = 0; j < 4; j++) {
        const int col = n0 + wn + j * 16 + fm;
        const float bv = bias[col];
#pragma unroll
        for (int i = 0; i < 4; i++) {
#pragma unroll
            for (int r = 0; r < 4; r++) {
                const int row = m0 + wm + i * 16 + fg * 4 + r;
                C[(size_t)row * Ndim + col] = acc[i][j][r] + bv;
            }
        }
    }
}

// ---------------------------------------------------------------------------
// Depthwise causal conv (width 3) on qT/kT rows + kv=conv(k)*v.
// Input qkvT: (6144, 8192) = [e][b*L + l], l-contiguous.  One block per (b,d),
// 256 threads x 8 l each.  Aligned bf16x8 body + 4B-aligned 2-elem halo load.
// Outputs qcT, kvT in (B, E, L).
// ---------------------------------------------------------------------------
__global__ __launch_bounds__(256) void dwconv_kv2(
    const bf16* __restrict__ qkvT,
    const float* __restrict__ cqw, const float* __restrict__ cqb,
    const float* __restrict__ ckw, const float* __restrict__ ckb,
    bf16* __restrict__ qcT, bf16* __restrict__ kvT) {
    const int bid = blockIdx.x;
    const int b = bid >> 11, d = bid & (DD - 1);
    const int tid = threadIdx.x;
    const int l = tid * 8;

    const bf16* qR = qkvT + (size_t)d * MM + b * LL;
    const bf16* kR = qkvT + (size_t)(2048 + d) * MM + b * LL;
    const bf16* vR = qkvT + (size_t)(4096 + d) * MM + b * LL;

    const float q0 = cqw[d * 3], q1 = cqw[d * 3 + 1], q2 = cqw[d * 3 + 2];
    const float k0 = ckw[d * 3], k1 = ckw[d * 3 + 1], k2 = ckw[d * 3 + 2];
    const float qb = cqb[d], kb = ckb[d];

    bf16x8 qx = *(const bf16x8*)(qR + l);
    bf16x8 kx = *(const bf16x8*)(kR + l);
    bf16x8 vx = *(const bf16x8*)(vR + l);

    float xq[10], xk[10];
    xq[0] = 0.f; xq[1] = 0.f; xk[0] = 0.f; xk[1] = 0.f;
    if (l >= 2) {
        bf16x2 qh = *(const bf16x2*)(qR + l - 2);
        bf16x2 kh = *(const bf16x2*)(kR + l - 2);
        xq[0] = (float)qh[0]; xq[1] = (float)qh[1];
        xk[0] = (float)kh[0]; xk[1] = (float)kh[1];
    }
#pragma unroll
    for (int c = 0; c < 8; c++) { xq[c + 2] = (float)qx[c]; xk[c + 2] = (float)kx[c]; }

    bf16x8 oq, okv;
#pragma unroll
    for (int c = 0; c < 8; c++) {
        float qc = q0 * xq[c] + q1 * xq[c + 1] + q2 * xq[c + 2] + qb;
        float kc = k0 * xk[c] + k1 * xk[c + 1] + k2 * xk[c + 2] + kb;
        oq[c] = (bf16)qc;
        okv[c] = (bf16)(kc * (float)vx[c]);
    }
    const size_t o = ((size_t)b * DD + d) * LL + l;
    *(bf16x8*)(qcT + o) = oq;
    *(bf16x8*)(kvT + o) = okv;
}

// ---------------------------------------------------------------------------
// Causal long conv + D-skip + q gating via Toeplitz MFMA.  (unchanged, R2)
// ---------------------------------------------------------------------------
__global__ __launch_bounds__(128, 2) void longconv_gate(
    const bf16* __restrict__ kvT, const bf16* __restrict__ qcT,
    const float* __restrict__ kern, const float* __restrict__ Dskip,
    bf16* __restrict__ ygT) {
    __shared__ bf16 kv_ls[4 * 2112];
    __shared__ float krev_f[2112];
    const int d = blockIdx.x;
    const int tid = threadIdx.x;

    {
        const int bb = tid >> 5, t32 = tid & 31;
#pragma unroll
        for (int c = 0; c < 8; ++c) {
            const int l = (c * 32 + t32) * 8;
            bf16x8 v = *(const bf16x8*)(kvT + ((size_t)bb * DD + d) * LL + l);
            *(bf16x8*)&kv_ls[2112 * bb + 48 + l] = v;
        }
        if (tid < 48) {
#pragma unroll
            for (int b2 = 0; b2 < 4; b2++) kv_ls[2112 * b2 + tid] = (bf16)0.f;
        } else if (tid < 64) {
#pragma unroll
            for (int b2 = 0; b2 < 4; b2++) kv_ls[2112 * b2 + 2048 + tid] = (bf16)0.f;
        }
    }
    {
        const float* kr = kern + (size_t)d * LL;
#pragma unroll
        for (int c = 0; c < 16; ++c) {
            const int x = c * 128 + tid;
            krev_f[x] = kr[2047 - x];
        }
        if (tid < 64) krev_f[2048 + tid] = 0.f;
    }
    __syncthreads();

    const int lane = tid & 63;
    const int w = __builtin_amdgcn_readfirstlane(tid >> 6);
    const int n = lane & 15, q = lane >> 4;
    const int b = n & 3, pp = n >> 2;
    const int cB = 2112 * b + 16 * pp + 8 * q;

    f32x4 acc[16];
#pragma unroll
    for (int s = 0; s < 16; s++) acc[s] = (f32x4){0.f, 0.f, 0.f, 0.f};

    for (int it = 0; it < 64; ++it) {
        const int as = 2031 - 32 * it - n + 8 * q;
        float af[8];
#pragma unroll
        for (int j = 0; j < 8; j++) af[j] = krev_f[as + j];
        bf16x8 a;
#pragma unroll
        for (int j = 0; j < 8; j++) a[j] = (bf16)af[j];

        const int bbase = cB + 64 * w + 32 - 32 * it;
#pragma unroll
        for (int h = 0; h < 2; ++h) {
            bf16x8 bfr[8];
#pragma unroll
            for (int s8 = 0; s8 < 8; s8++) {
                const int s = h * 8 + s8;
                if (it <= 4 * s + 2 * w + 1)
                    bfr[s8] = *(const bf16x8*)&kv_ls[bbase + 128 * s];
            }
#pragma unroll
            for (int s8 = 0; s8 < 8; s8++) {
                const int s = h * 8 + s8;
                if (it <= 4 * s + 2 * w + 1)
                    acc[s] = __builtin_amdgcn_mfma_f32_16x16x32_bf16(
                        a, bfr[s8], acc[s], 0, 0, 0);
            }
        }
    }

    const float dsk = Dskip[d];
#pragma unroll
    for (int s = 0; s < 16; s++) {
        const int i = 2 * s + w;
        const int l = 64 * i + 16 * pp + 4 * q;
        const size_t gb = ((size_t)b * DD + d) * LL + l;
        bf16x4 qc4 = *(const bf16x4*)&qcT[gb];
        bf16x4 kv4 = *(const bf16x4*)&kv_ls[2112 * b + 48 + l];
        bf16x4 o;
#pragma unroll
        for (int r = 0; r < 4; r++) {
            float val = (acc[s][r] + (float)kv4[r] * dsk) * (float)qc4[r];
            o[r] = (bf16)val;
        }
        *(bf16x4*)&ygT[gb] = o;
    }
}

// ---------------------------------------------------------------------------
// bf16 transpose (B, D, L) -> (B, L, D), 32x32 tiles (unchanged)
// ---------------------------------------------------------------------------
__global__ __launch_bounds__(256) void transpose_dl(const bf16* __restrict__ src,
                                                    bf16* __restrict__ dst) {
    __shared__ bf16 ts[32][33];
    const int b = blockIdx.z;
    const int l0 = blockIdx.x * 32, d0 = blockIdx.y * 32;
    const int tid = threadIdx.x;
    const int c = tid & 31, r0 = tid >> 5;
#pragma unroll
    for (int p = 0; p < 4; p++) {
        int r = r0 + p * 8;
        ts[r][c] = src[((size_t)b * DD + d0 + r) * LL + l0 + c];
    }
    __syncthreads();
#pragma unroll
    for (int p = 0; p < 4; p++) {
        int r = r0 + p * 8;
        dst[((size_t)b * LL + l0 + r) * DD + d0 + c] = ts[c][r];
    }
}

// ---------------------------------------------------------------------------
// launch
// ---------------------------------------------------------------------------
extern "C" void kernel_launch(void* const* d_in, const int* in_sizes, int n_in,
                              void* d_out, int out_size, void* d_ws, size_t ws_size,
                              hipStream_t stream) {
    const float* u   = (const float*)d_in[0];
    const float* Wq  = (const float*)d_in[1];
    const float* bq  = (const float*)d_in[2];
    const float* Wk  = (const float*)d_in[3];
    const float* bk  = (const float*)d_in[4];
    const float* Wv  = (const float*)d_in[5];
    const float* bv  = (const float*)d_in[6];
    const float* cqw = (const float*)d_in[7];
    const float* cqb = (const float*)d_in[8];
    const float* ckw = (const float*)d_in[9];
    const float* ckb = (const float*)d_in[10];
    const float* ssm = (const float*)d_in[11];
    const float* Dsk = (const float*)d_in[12];
    const float* Wo  = (const float*)d_in[13];
    const float* bo  = (const float*)d_in[14];

    char* w = (char*)d_ws;
    bf16* u_bf    = (bf16*)(w);                  // 33.55 MB (reused as ygT)
    bf16* Wqkv_bf = (bf16*)(w + 33554432ull);    // 25.2 MB (q|k|v rows concat)
    bf16* Wo_bf   = (bf16*)(w + 58720256ull);    // 8.39 MB
    bf16* qkvT    = (bf16*)(w + 67108864ull);    // 100.7 MB (6144 x 8192)
    bf16* qcT     = (bf16*)(w + 167772160ull);   // 33.55 MB
    bf16* kvT     = (bf16*)(w + 201326592ull);   // 33.55 MB
    // total: 234,881,024 B

    // fp32 -> bf16 conversions (Wq|Wk|Wv into contiguous Wqkv)
    cvt_f32_bf16<<<8192, 256, 0, stream>>>(u, u_bf, MM * DD / 8);
    cvt_f32_bf16<<<2048, 256, 0, stream>>>(Wq, Wqkv_bf, DD * DD / 8);
    cvt_f32_bf16<<<2048, 256, 0, stream>>>(Wk, Wqkv_bf + 4194304, DD * DD / 8);
    cvt_f32_bf16<<<2048, 256, 0, stream>>>(Wv, Wqkv_bf + 8388608, DD * DD / 8);
    cvt_f32_bf16<<<2048, 256, 0, stream>>>(Wo, Wo_bf, DD * DD / 8);

    // fused q/k/v projection -> transposed output (E, B*L)
    dim3 gq(MM / 128, NN / 128);
    gemm_qkv<<<gq, 256, 0, stream>>>(u_bf, Wqkv_bf, bq, bk, bv, qkvT);

    // depthwise convs + kv (row-wise on transposed layout)
    dwconv_kv2<<<BB * DD, 256, 0, stream>>>(qkvT, cqw, cqb, ckw, ckb, qcT, kvT);

    // causal long conv (Toeplitz MFMA) + gating
    bf16* ygT = u_bf; // reuse
    longconv_gate<<<DD, 128, 0, stream>>>(kvT, qcT, ssm, Dsk, ygT);

    // transpose back to (B,L,E)
    bf16* ygTT = qkvT; // reuse
    dim3 gc(LL / 32, DD / 32, BB);
    transpose_dl<<<gc, 256, 0, stream>>>(ygT, ygTT);

    // output projection -> fp32 d_out
    dim3 gg(MM / 128, DD / 128);
    gemm_bt_f32<<<gg, 256, 0, stream>>>(ygTT, Wo_bf, bo, (float*)d_out, DD, DD);
}